// Round 10
// baseline (234.277 us; speedup 1.0000x reference)
//
#include <hip/hip_runtime.h>

#define NCH 128      // channels C
#define NGR 256      // graphs B
#define NBR 32       // branches K
#define NEG_SLOPE 0.01f

typedef __attribute__((ext_vector_type(8))) short bf16x8;   // MFMA A/B operand
typedef __attribute__((ext_vector_type(4))) float f32x4;    // MFMA C/D (16x16)

constexpr int TROWS = 32;    // nodes per LDS tile (16 KB), one K-group
constexpr int NSPLIT = 4;    // blocks per graph (quarter segments)

__device__ inline unsigned short rtne_bf16(float x) {
    unsigned u = __float_as_uint(x);
    return (unsigned short)((u + 0x7FFFu + ((u >> 16) & 1u)) >> 16);
}
__device__ inline unsigned pack_hl(float v) {
    const unsigned u = __float_as_uint(v);
    const unsigned short h = (unsigned short)(u >> 16);          // truncated hi
    const float hf = __uint_as_float(u & 0xFFFF0000u);
    const unsigned short l = rtne_bf16(v - hf);                  // residual lo
    return ((unsigned)h << 16) | (unsigned)l;
}

// -------- Phase 1: streaming onehot-MFMA segment-sum, double-buffered.
// 1024 blocks (4 per graph, quarter-segment each), 512 threads (8 waves),
// 3-4 blocks/CU for barrier-group desync.
__global__ __launch_bounds__(512, 6) void scatter_mfma(
    const float* __restrict__ node_embed,   // [N, C]
    const int*   __restrict__ batch,        // [N] sorted
    const int*   __restrict__ branch,       // [N] in [0,K)
    float*       __restrict__ part,         // [NSPLIT][B*K, C] fully overwritten
    int*         __restrict__ max_b_part,   // [NSPLIT][B]      fully overwritten
    int n_nodes)
{
    __shared__ float buf[2][TROWS][NCH] __attribute__((aligned(16)));  // 32 KB
    __shared__ int   sbr_i[2][64]       __attribute__((aligned(16))); // id tiles (64-padded)
    __shared__ int   seg_s[2];
    __shared__ int   wm[8];

    const int t    = threadIdx.x;
    const int bid  = blockIdx.x;
    const int g    = bid >> 2;
    const int q    = bid & 3;
    const int wave = t >> 6;
    const int lane = t & 63;
    const int c    = wave;           // channel tile 0..7 (16 ch each)
    const int gq   = lane >> 4;
    const int m    = lane & 15;

    if (t < 2) {
        const int target = g + t;
        int lo = 0, hi = n_nodes;
        while (lo < hi) { int mid = (lo + hi) >> 1; if (batch[mid] < target) lo = mid + 1; else hi = mid; }
        seg_s[t] = lo;
    }
    __syncthreads();
    const int s0 = seg_s[0], s1 = seg_s[1];
    const int nt_tot = (s1 - s0 + TROWS - 1) / TROWS;
    const int per    = (nt_tot + NSPLIT - 1) / NSPLIT;
    const int t0     = q * per;
    const int t1     = min(t0 + per, nt_tot);
    const int nt     = max(t1 - t0, 0);
    const int sa     = s0 + t0 * TROWS;

    // stage one 16 KB tile (8 waves x 2 x 1KB) + 256B ids (wave 0)
    auto stage = [&](int ti, int bi) {
        const int c0n = sa + ti * TROWS;
        #pragma unroll
        for (int u = 0; u < 2; ++u) {
            const int koff = (u * 8 + wave) * 1024;
            const int lanebyte = koff + lane * 16;
            const int rowg = c0n + (lanebyte >> 9);
            const char* src = (const char*)node_embed + ((size_t)c0n * 512 + (size_t)lanebyte);
            if (rowg >= s1) src = (const char*)node_embed;   // clamp: valid mem, masked by A=0
            __builtin_amdgcn_global_load_lds(
                (const __attribute__((address_space(1))) void*)src,
                (__attribute__((address_space(3))) void*)((char*)&buf[bi][0][0] + koff),
                16, 0, 0);
        }
        if (wave == 0) {                                     // 64 lanes x 4B (32 ids + pad)
            const int i0 = min(c0n + lane, n_nodes - 1);
            __builtin_amdgcn_global_load_lds(
                (const __attribute__((address_space(1))) void*)(branch + i0),
                (__attribute__((address_space(3))) void*)((char*)&sbr_i[bi][0]), 4, 0, 0);
        }
    };

    f32x4 acc0 = {0.f, 0.f, 0.f, 0.f};   // slots 0..15
    f32x4 acc1 = {0.f, 0.f, 0.f, 0.f};   // slots 16..31
    int mymax = -1;

    auto compute = [&](int ti, int bi) {
        const int rem = s1 - (sa + ti * TROWS);              // >= TROWS except segment-final tile
        const int4 i0 = *(const int4*)&sbr_i[bi][gq * 8];
        const int4 i1 = *(const int4*)&sbr_i[bi][gq * 8 + 4];
        const int idv[8] = {i0.x, i0.y, i0.z, i0.w, i1.x, i1.y, i1.z, i1.w};
        bf16x8 a0, a1, bh, bl;
        #pragma unroll
        for (int j = 0; j < 8; ++j) {
            const float v = buf[bi][gq * 8 + j][c * 16 + m];
            const unsigned u = __float_as_uint(v);
            bh[j] = (short)(unsigned short)(u >> 16);
            const float hf = __uint_as_float(u & 0xFFFF0000u);
            bl[j] = (short)rtne_bf16(v - hf);
            const bool val = (gq * 8 + j) < rem;
            a0[j] = (val && idv[j] == m)      ? (short)0x3F80 : (short)0;
            a1[j] = (val && idv[j] == m + 16) ? (short)0x3F80 : (short)0;
            if (val) mymax = max(mymax, idv[j]);
        }
        acc0 = __builtin_amdgcn_mfma_f32_16x16x32_bf16(a0, bh, acc0, 0, 0, 0);
        acc0 = __builtin_amdgcn_mfma_f32_16x16x32_bf16(a0, bl, acc0, 0, 0, 0);
        acc1 = __builtin_amdgcn_mfma_f32_16x16x32_bf16(a1, bh, acc1, 0, 0, 0);
        acc1 = __builtin_amdgcn_mfma_f32_16x16x32_bf16(a1, bl, acc1, 0, 0, 0);
    };

    if (nt > 0) {
        stage(0, 0);
        for (int ti = 0; ti < nt; ++ti) {
            const int bi = ti & 1;
            // issue next tile into the buffer whose readers finished at the
            // previous iteration's trailing barrier; keeps 1 tile in flight
            // across the wait below.
            if (ti + 1 < nt) stage(ti + 1, bi ^ 1);
            if (ti + 1 < nt) {
                if (wave == 0) asm volatile("s_waitcnt vmcnt(3)" ::: "memory");
                else           asm volatile("s_waitcnt vmcnt(2)" ::: "memory");
            } else {
                asm volatile("s_waitcnt vmcnt(0)" ::: "memory");
            }
            __builtin_amdgcn_s_barrier();
            __builtin_amdgcn_sched_barrier(0);
            compute(ti, bi);
            __builtin_amdgcn_s_barrier();                    // readers done with buf[bi]
            __builtin_amdgcn_sched_barrier(0);
        }
    }

    // non-atomic writeout: wave owns its full 16-ch tile (both slot halves)
    {
        const int sr = gq * 4;                               // D row = (lane>>4)*4 + reg [m89]
        float* be = part + (size_t)q * NGR * NBR * NCH
                  + (size_t)g * NBR * NCH + (size_t)c * 16 + m;
        #pragma unroll
        for (int r = 0; r < 4; ++r) {
            be[(sr + r) * NCH]      = acc0[r];               // slots 0..15
            be[(16 + sr + r) * NCH] = acc1[r];               // slots 16..31
        }
    }

    // per-graph-quarter branch max
    int v = mymax;
    #pragma unroll
    for (int off = 32; off > 0; off >>= 1) v = max(v, __shfl_down(v, off));
    if (lane == 0) wm[wave] = v;
    __syncthreads();
    if (t == 0) {
        int mb = wm[0];
        #pragma unroll
        for (int i = 1; i < 8; ++i) mb = max(mb, wm[i]);
        max_b_part[q * NGR + g] = mb;
    }
}

// -------- Phase 2: MFMA MLP + masked per-graph sum. One block per graph, 8 waves.
__global__ __launch_bounds__(512) void mlp_mfma(
    const float* __restrict__ part,         // [NSPLIT][B*K, C]
    const int*   __restrict__ max_b_part,   // [NSPLIT][B]
    const float* __restrict__ W1,           // [C, C] row-major
    const float* __restrict__ b1,           // [C]
    const float* __restrict__ W2,           // [C]
    const float* __restrict__ b2,           // [1]
    float*       __restrict__ out)          // [B]
{
    __shared__ unsigned w1p[128 * 130];     // hi/lo packed W1, padded stride (66.5 KB)
    __shared__ unsigned epk[32 * 132];      // hi/lo packed E,  padded stride (16.9 KB)
    __shared__ float    red[32 * 8];        // per-slot per-ctile partials (1 KB)

    const int t    = threadIdx.x;
    const int g    = blockIdx.x;
    const int wave = t >> 6;
    const int lane = t & 63;
    const int gq   = lane >> 4;
    const int m    = lane & 15;
    const int sh   = wave & 1;       // slot half (rows sh*16 .. +16)
    const int c0   = wave >> 1;      // c-tiles c0 and c0+4

    // stage W1 -> packed LDS: 8 float4 per thread, coalesced
    #pragma unroll
    for (int i = 0; i < 8; ++i) {
        const int eb  = i * 2048 + t * 4;
        const int row = eb >> 7, col = eb & 127;
        const float4 w = *(const float4*)&W1[eb];
        unsigned* d = &w1p[row * 130 + col];
        *(uint2*)d       = make_uint2(pack_hl(w.x), pack_hl(w.y));
        *(uint2*)(d + 2) = make_uint2(pack_hl(w.z), pack_hl(w.w));
    }
    // stage E = sum of NSPLIT partials -> packed LDS: slot = t>>4, 8 channels each
    {
        const int slot = t >> 4, kb = (t & 15) * 8;
        const size_t base = ((size_t)g * NBR + slot) * NCH + kb;
        const size_t pstride = (size_t)NGR * NBR * NCH;
        float4 e0 = *(const float4*)&part[base];
        float4 e1 = *(const float4*)&part[base + 4];
        #pragma unroll
        for (int pp = 1; pp < NSPLIT; ++pp) {
            const float4 f0 = *(const float4*)&part[pp * pstride + base];
            const float4 f1 = *(const float4*)&part[pp * pstride + base + 4];
            e0.x += f0.x; e0.y += f0.y; e0.z += f0.z; e0.w += f0.w;
            e1.x += f1.x; e1.y += f1.y; e1.z += f1.z; e1.w += f1.w;
        }
        unsigned* d = &epk[slot * 132 + kb];
        *(uint4*)d       = make_uint4(pack_hl(e0.x), pack_hl(e0.y), pack_hl(e0.z), pack_hl(e0.w));
        *(uint4*)(d + 4) = make_uint4(pack_hl(e1.x), pack_hl(e1.y), pack_hl(e1.z), pack_hl(e1.w));
    }
    const float b1v0 = b1[c0 * 16 + m],      b1v1 = b1[(c0 + 4) * 16 + m];
    const float w2v0 = W2[c0 * 16 + m],      w2v1 = W2[(c0 + 4) * 16 + m];
    __syncthreads();

    f32x4 accA = {0.f, 0.f, 0.f, 0.f};       // cols c0*16..
    f32x4 accB = {0.f, 0.f, 0.f, 0.f};       // cols (c0+4)*16..
    #pragma unroll
    for (int ks = 0; ks < 4; ++ks) {
        const int k0 = ks * 32;
        const unsigned* ap = &epk[(sh * 16 + m) * 132 + k0 + gq * 8];
        const uint4 aw0 = *(const uint4*)ap;
        const uint4 aw1 = *(const uint4*)(ap + 4);
        const unsigned aw[8] = {aw0.x, aw0.y, aw0.z, aw0.w, aw1.x, aw1.y, aw1.z, aw1.w};
        bf16x8 ah, al;
        #pragma unroll
        for (int j = 0; j < 8; ++j) { ah[j] = (short)(aw[j] >> 16); al[j] = (short)(aw[j] & 0xFFFFu); }

        bf16x8 bh, blo;
        #pragma unroll
        for (int j = 0; j < 8; ++j) {
            const unsigned w = w1p[(k0 + gq * 8 + j) * 130 + c0 * 16 + m];
            bh[j] = (short)(w >> 16); blo[j] = (short)(w & 0xFFFFu);
        }
        accA = __builtin_amdgcn_mfma_f32_16x16x32_bf16(ah, bh,  accA, 0, 0, 0);
        accA = __builtin_amdgcn_mfma_f32_16x16x32_bf16(al, bh,  accA, 0, 0, 0);
        accA = __builtin_amdgcn_mfma_f32_16x16x32_bf16(ah, blo, accA, 0, 0, 0);

        #pragma unroll
        for (int j = 0; j < 8; ++j) {
            const unsigned w = w1p[(k0 + gq * 8 + j) * 130 + (c0 + 4) * 16 + m];
            bh[j] = (short)(w >> 16); blo[j] = (short)(w & 0xFFFFu);
        }
        accB = __builtin_amdgcn_mfma_f32_16x16x32_bf16(ah, bh,  accB, 0, 0, 0);
        accB = __builtin_amdgcn_mfma_f32_16x16x32_bf16(al, bh,  accB, 0, 0, 0);
        accB = __builtin_amdgcn_mfma_f32_16x16x32_bf16(ah, blo, accB, 0, 0, 0);
    }

    // leaky_relu + *W2, reduce over this tile's 16 cols, stash per (slot, ctile)
    #pragma unroll
    for (int r = 0; r < 4; ++r) {
        float h0 = accA[r] + b1v0;
        h0 = (h0 >= 0.f) ? h0 : NEG_SLOPE * h0;
        float s0v = h0 * w2v0;
        float h1 = accB[r] + b1v1;
        h1 = (h1 >= 0.f) ? h1 : NEG_SLOPE * h1;
        float s1v = h1 * w2v1;
        #pragma unroll
        for (int off = 1; off < 16; off <<= 1) {
            s0v += __shfl_xor(s0v, off);
            s1v += __shfl_xor(s1v, off);
        }
        if (m == 0) {
            const int slot = sh * 16 + gq * 4 + r;           // D row = gq*4 + r [m89]
            red[slot * 8 + c0]     = s0v;
            red[slot * 8 + c0 + 4] = s1v;
        }
    }
    __syncthreads();

    if (t < 64) {
        const int rr = lane & 31;
        float v = 0.f;
        #pragma unroll
        for (int cc = 0; cc < 8; ++cc) v += red[rr * 8 + cc];
        int mb = max_b_part[g];
        #pragma unroll
        for (int pp = 1; pp < NSPLIT; ++pp) mb = max(mb, max_b_part[pp * NGR + g]);
        float val = (lane < 32 && rr <= mb) ? (v + b2[0]) : 0.f;
        #pragma unroll
        for (int off = 32; off > 0; off >>= 1) val += __shfl_down(val, off);
        if (t == 0) out[g] = val;
    }
}

extern "C" void kernel_launch(void* const* d_in, const int* in_sizes, int n_in,
                              void* d_out, int out_size, void* d_ws, size_t ws_size,
                              hipStream_t stream) {
    const float* node_embed = (const float*)d_in[0];
    const int*   batch      = (const int*)d_in[1];
    const int*   branch     = (const int*)d_in[2];
    const float* W1         = (const float*)d_in[3];
    const float* b1         = (const float*)d_in[4];
    const float* W2         = (const float*)d_in[5];
    const float* b2         = (const float*)d_in[6];
    float*       out        = (float*)d_out;

    const int n_nodes = in_sizes[0] / NCH;   // 2,000,000

    float* part = (float*)d_ws;                                   // NSPLIT x 4 MB partials
    int*   max_b_part = (int*)((char*)d_ws
                       + (size_t)NSPLIT * NGR * NBR * NCH * sizeof(float));

    // all workspace buffers fully overwritten non-atomically every call
    scatter_mfma<<<NSPLIT * NGR, 512, 0, stream>>>(node_embed, batch, branch,
                                                   part, max_b_part, n_nodes);
    mlp_mfma<<<NGR, 512, 0, stream>>>(part, max_b_part, W1, b1, W2, b2, out);
}

// Round 11
// 208.451 us; speedup vs baseline: 1.1239x; 1.1239x over previous
//
#include <hip/hip_runtime.h>

#define NCH 128      // channels C
#define NGR 256      // graphs B
#define NBR 32       // branches K
#define NEG_SLOPE 0.01f

typedef __attribute__((ext_vector_type(8))) short bf16x8;   // MFMA A/B operand
typedef __attribute__((ext_vector_type(4))) float f32x4;    // MFMA C/D (16x16)

constexpr int TROWS = 32;    // nodes per LDS tile (16 KB), one K-group
constexpr int NBUF  = 4;     // quad-buffer: 3 tiles in flight across waits

__device__ inline unsigned short rtne_bf16(float x) {
    unsigned u = __float_as_uint(x);
    return (unsigned short)((u + 0x7FFFu + ((u >> 16) & 1u)) >> 16);
}
__device__ inline unsigned pack_hl(float v) {
    const unsigned u = __float_as_uint(v);
    const unsigned short h = (unsigned short)(u >> 16);          // truncated hi
    const float hf = __uint_as_float(u & 0xFFFF0000u);
    const unsigned short l = rtne_bf16(v - hf);                  // residual lo
    return ((unsigned)h << 16) | (unsigned)l;
}

// -------- Phase 1: streaming onehot-MFMA segment-sum, quad-buffered.
// 512 blocks (2 per graph, half-segment each), 512 threads (8 waves), 2 blocks/CU.
__global__ __launch_bounds__(512, 4) void scatter_mfma(
    const float* __restrict__ node_embed,   // [N, C]
    const int*   __restrict__ batch,        // [N] sorted
    const int*   __restrict__ branch,       // [N] in [0,K)
    float*       __restrict__ part,         // [2][B*K, C] fully overwritten
    int*         __restrict__ max_b_part,   // [2][B]      fully overwritten
    int n_nodes)
{
    __shared__ float buf[NBUF][TROWS][NCH] __attribute__((aligned(16)));  // 64 KB
    __shared__ int   sbr_i[NBUF][64]       __attribute__((aligned(16))); // id tiles
    __shared__ int   seg_s[2];
    __shared__ int   wm[8];

    const int t    = threadIdx.x;
    const int bid  = blockIdx.x;
    const int g    = bid >> 1;
    const int half = bid & 1;
    const int wave = t >> 6;
    const int lane = t & 63;
    const int c    = wave;           // channel tile 0..7 (16 ch each)
    const int gq   = lane >> 4;
    const int m    = lane & 15;

    if (t < 2) {
        const int target = g + t;
        int lo = 0, hi = n_nodes;
        while (lo < hi) { int mid = (lo + hi) >> 1; if (batch[mid] < target) lo = mid + 1; else hi = mid; }
        seg_s[t] = lo;
    }
    __syncthreads();
    const int s0 = seg_s[0], s1 = seg_s[1];
    const int nt_tot = (s1 - s0 + TROWS - 1) / TROWS;
    const int ntA    = (nt_tot + 1) >> 1;
    const int sa     = half ? s0 + ntA * TROWS : s0;
    const int nt     = half ? nt_tot - ntA : ntA;

    // stage one 16 KB tile (8 waves x 2 x 1KB) + 256B ids (wave 0). 2 (3) insts/wave.
    auto stage = [&](int ti, int bi) {
        const int c0n = sa + ti * TROWS;
        #pragma unroll
        for (int u = 0; u < 2; ++u) {
            const int koff = (u * 8 + wave) * 1024;
            const int lanebyte = koff + lane * 16;
            const int rowg = c0n + (lanebyte >> 9);
            const char* src = (const char*)node_embed + ((size_t)c0n * 512 + (size_t)lanebyte);
            if (rowg >= s1) src = (const char*)node_embed;   // clamp: valid mem, masked by A=0
            __builtin_amdgcn_global_load_lds(
                (const __attribute__((address_space(1))) void*)src,
                (__attribute__((address_space(3))) void*)((char*)&buf[bi][0][0] + koff),
                16, 0, 0);
        }
        if (wave == 0) {                                     // 64 lanes x 4B (32 ids + pad)
            const int i0 = min(c0n + lane, n_nodes - 1);
            __builtin_amdgcn_global_load_lds(
                (const __attribute__((address_space(1))) void*)(branch + i0),
                (__attribute__((address_space(3))) void*)((char*)&sbr_i[bi][0]), 4, 0, 0);
        }
    };

    // wait so that the newest k tiles may remain in flight (everything older landed)
    auto wait_keep = [&](int k) {
        if (wave == 0) {                                     // 3 loads/tile for wave 0
            if (k == 3)      asm volatile("s_waitcnt vmcnt(9)" ::: "memory");
            else if (k == 2) asm volatile("s_waitcnt vmcnt(6)" ::: "memory");
            else if (k == 1) asm volatile("s_waitcnt vmcnt(3)" ::: "memory");
            else             asm volatile("s_waitcnt vmcnt(0)" ::: "memory");
        } else {                                             // 2 loads/tile
            if (k == 3)      asm volatile("s_waitcnt vmcnt(6)" ::: "memory");
            else if (k == 2) asm volatile("s_waitcnt vmcnt(4)" ::: "memory");
            else if (k == 1) asm volatile("s_waitcnt vmcnt(2)" ::: "memory");
            else             asm volatile("s_waitcnt vmcnt(0)" ::: "memory");
        }
    };

    f32x4 acc0 = {0.f, 0.f, 0.f, 0.f};   // slots 0..15
    f32x4 acc1 = {0.f, 0.f, 0.f, 0.f};   // slots 16..31
    int mymax = -1;

    auto compute = [&](int ti, int bi) {
        const int rem = s1 - (sa + ti * TROWS);              // >= TROWS on full tiles
        const int4 i0 = *(const int4*)&sbr_i[bi][gq * 8];
        const int4 i1 = *(const int4*)&sbr_i[bi][gq * 8 + 4];
        const int idv[8] = {i0.x, i0.y, i0.z, i0.w, i1.x, i1.y, i1.z, i1.w};
        bf16x8 a0, a1, bh, bl;
        #pragma unroll
        for (int j = 0; j < 8; ++j) {
            const float v = buf[bi][gq * 8 + j][c * 16 + m];
            const unsigned u = __float_as_uint(v);
            bh[j] = (short)(unsigned short)(u >> 16);
            const float hf = __uint_as_float(u & 0xFFFF0000u);
            bl[j] = (short)rtne_bf16(v - hf);
            const bool val = (gq * 8 + j) < rem;
            a0[j] = (val && idv[j] == m)      ? (short)0x3F80 : (short)0;
            a1[j] = (val && idv[j] == m + 16) ? (short)0x3F80 : (short)0;
            if (val) mymax = max(mymax, idv[j]);
        }
        acc0 = __builtin_amdgcn_mfma_f32_16x16x32_bf16(a0, bh, acc0, 0, 0, 0);
        acc0 = __builtin_amdgcn_mfma_f32_16x16x32_bf16(a0, bl, acc0, 0, 0, 0);
        acc1 = __builtin_amdgcn_mfma_f32_16x16x32_bf16(a1, bh, acc1, 0, 0, 0);
        acc1 = __builtin_amdgcn_mfma_f32_16x16x32_bf16(a1, bl, acc1, 0, 0, 0);
    };

    if (nt > 0) {
        stage(0, 0);
        if (nt > 1) stage(1, 1);
        if (nt > 2) stage(2, 2);
        wait_keep(min(nt - 1, 2));                           // tile 0 landed
        __builtin_amdgcn_s_barrier();
        __builtin_amdgcn_sched_barrier(0);

        for (int ti = 0; ti < nt; ++ti) {
            const int bi = ti & (NBUF - 1);
            // issue next stage FIRST: buffer (ti+3)%4 was last read in iter ti-1
            // (behind that iteration's trailing barrier) -> 3 tiles in flight
            // across the wait below.
            if (ti + 3 < nt) stage(ti + 3, (ti + 3) & (NBUF - 1));
            wait_keep(min(nt - 1 - ti, 3));                  // tile ti landed
            __builtin_amdgcn_s_barrier();
            __builtin_amdgcn_sched_barrier(0);
            compute(ti, bi);
            __builtin_amdgcn_s_barrier();                    // readers done with buf[bi]
            __builtin_amdgcn_sched_barrier(0);
        }
    }

    // non-atomic writeout: wave owns its full 16-ch tile (both slot halves)
    {
        const int sr = gq * 4;                               // D row = (lane>>4)*4 + reg [m89]
        float* be = part + (size_t)half * NGR * NBR * NCH
                  + (size_t)g * NBR * NCH + (size_t)c * 16 + m;
        #pragma unroll
        for (int r = 0; r < 4; ++r) {
            be[(sr + r) * NCH]      = acc0[r];               // slots 0..15
            be[(16 + sr + r) * NCH] = acc1[r];               // slots 16..31
        }
    }

    // per-graph-half branch max
    int v = mymax;
    #pragma unroll
    for (int off = 32; off > 0; off >>= 1) v = max(v, __shfl_down(v, off));
    if (lane == 0) wm[wave] = v;
    __syncthreads();
    if (t == 0) {
        int mb = wm[0];
        #pragma unroll
        for (int i = 1; i < 8; ++i) mb = max(mb, wm[i]);
        max_b_part[half * NGR + g] = mb;
    }
}

// -------- Phase 2: MFMA MLP + masked per-graph sum. One block per graph, 8 waves.
__global__ __launch_bounds__(512) void mlp_mfma(
    const float* __restrict__ part,         // [2][B*K, C]
    const int*   __restrict__ max_b_part,   // [2][B]
    const float* __restrict__ W1,           // [C, C] row-major
    const float* __restrict__ b1,           // [C]
    const float* __restrict__ W2,           // [C]
    const float* __restrict__ b2,           // [1]
    float*       __restrict__ out)          // [B]
{
    __shared__ unsigned w1p[128 * 130];     // hi/lo packed W1, padded stride (66.5 KB)
    __shared__ unsigned epk[32 * 132];      // hi/lo packed E,  padded stride (16.9 KB)
    __shared__ float    red[32 * 8];        // per-slot per-ctile partials (1 KB)

    const int t    = threadIdx.x;
    const int g    = blockIdx.x;
    const int wave = t >> 6;
    const int lane = t & 63;
    const int gq   = lane >> 4;
    const int m    = lane & 15;
    const int sh   = wave & 1;       // slot half (rows sh*16 .. +16)
    const int c0   = wave >> 1;      // c-tiles c0 and c0+4

    // stage W1 -> packed LDS: 8 float4 per thread, coalesced
    #pragma unroll
    for (int i = 0; i < 8; ++i) {
        const int eb  = i * 2048 + t * 4;
        const int row = eb >> 7, col = eb & 127;
        const float4 w = *(const float4*)&W1[eb];
        unsigned* d = &w1p[row * 130 + col];
        *(uint2*)d       = make_uint2(pack_hl(w.x), pack_hl(w.y));
        *(uint2*)(d + 2) = make_uint2(pack_hl(w.z), pack_hl(w.w));
    }
    // stage E = partA + partB -> packed LDS: slot = t>>4, 8 channels each
    {
        const int slot = t >> 4, kb = (t & 15) * 8;
        const size_t base = ((size_t)g * NBR + slot) * NCH + kb;
        const float* pB = part + (size_t)NGR * NBR * NCH;
        float4 e0 = *(const float4*)&part[base];
        float4 e1 = *(const float4*)&part[base + 4];
        const float4 f0 = *(const float4*)&pB[base];
        const float4 f1 = *(const float4*)&pB[base + 4];
        e0.x += f0.x; e0.y += f0.y; e0.z += f0.z; e0.w += f0.w;
        e1.x += f1.x; e1.y += f1.y; e1.z += f1.z; e1.w += f1.w;
        unsigned* d = &epk[slot * 132 + kb];
        *(uint4*)d       = make_uint4(pack_hl(e0.x), pack_hl(e0.y), pack_hl(e0.z), pack_hl(e0.w));
        *(uint4*)(d + 4) = make_uint4(pack_hl(e1.x), pack_hl(e1.y), pack_hl(e1.z), pack_hl(e1.w));
    }
    const float b1v0 = b1[c0 * 16 + m],      b1v1 = b1[(c0 + 4) * 16 + m];
    const float w2v0 = W2[c0 * 16 + m],      w2v1 = W2[(c0 + 4) * 16 + m];
    __syncthreads();

    f32x4 accA = {0.f, 0.f, 0.f, 0.f};       // cols c0*16..
    f32x4 accB = {0.f, 0.f, 0.f, 0.f};       // cols (c0+4)*16..
    #pragma unroll
    for (int ks = 0; ks < 4; ++ks) {
        const int k0 = ks * 32;
        const unsigned* ap = &epk[(sh * 16 + m) * 132 + k0 + gq * 8];
        const uint4 aw0 = *(const uint4*)ap;
        const uint4 aw1 = *(const uint4*)(ap + 4);
        const unsigned aw[8] = {aw0.x, aw0.y, aw0.z, aw0.w, aw1.x, aw1.y, aw1.z, aw1.w};
        bf16x8 ah, al;
        #pragma unroll
        for (int j = 0; j < 8; ++j) { ah[j] = (short)(aw[j] >> 16); al[j] = (short)(aw[j] & 0xFFFFu); }

        bf16x8 bh, blo;
        #pragma unroll
        for (int j = 0; j < 8; ++j) {
            const unsigned w = w1p[(k0 + gq * 8 + j) * 130 + c0 * 16 + m];
            bh[j] = (short)(w >> 16); blo[j] = (short)(w & 0xFFFFu);
        }
        accA = __builtin_amdgcn_mfma_f32_16x16x32_bf16(ah, bh,  accA, 0, 0, 0);
        accA = __builtin_amdgcn_mfma_f32_16x16x32_bf16(al, bh,  accA, 0, 0, 0);
        accA = __builtin_amdgcn_mfma_f32_16x16x32_bf16(ah, blo, accA, 0, 0, 0);

        #pragma unroll
        for (int j = 0; j < 8; ++j) {
            const unsigned w = w1p[(k0 + gq * 8 + j) * 130 + (c0 + 4) * 16 + m];
            bh[j] = (short)(w >> 16); blo[j] = (short)(w & 0xFFFFu);
        }
        accB = __builtin_amdgcn_mfma_f32_16x16x32_bf16(ah, bh,  accB, 0, 0, 0);
        accB = __builtin_amdgcn_mfma_f32_16x16x32_bf16(al, bh,  accB, 0, 0, 0);
        accB = __builtin_amdgcn_mfma_f32_16x16x32_bf16(ah, blo, accB, 0, 0, 0);
    }

    // leaky_relu + *W2, reduce over this tile's 16 cols, stash per (slot, ctile)
    #pragma unroll
    for (int r = 0; r < 4; ++r) {
        float h0 = accA[r] + b1v0;
        h0 = (h0 >= 0.f) ? h0 : NEG_SLOPE * h0;
        float s0v = h0 * w2v0;
        float h1 = accB[r] + b1v1;
        h1 = (h1 >= 0.f) ? h1 : NEG_SLOPE * h1;
        float s1v = h1 * w2v1;
        #pragma unroll
        for (int off = 1; off < 16; off <<= 1) {
            s0v += __shfl_xor(s0v, off);
            s1v += __shfl_xor(s1v, off);
        }
        if (m == 0) {
            const int slot = sh * 16 + gq * 4 + r;           // D row = gq*4 + r [m89]
            red[slot * 8 + c0]     = s0v;
            red[slot * 8 + c0 + 4] = s1v;
        }
    }
    __syncthreads();

    if (t < 64) {
        const int rr = lane & 31;
        float v = 0.f;
        #pragma unroll
        for (int cc = 0; cc < 8; ++cc) v += red[rr * 8 + cc];
        const int mb = max(max_b_part[g], max_b_part[NGR + g]);
        float val = (lane < 32 && rr <= mb) ? (v + b2[0]) : 0.f;
        #pragma unroll
        for (int off = 32; off > 0; off >>= 1) val += __shfl_down(val, off);
        if (t == 0) out[g] = val;
    }
}

extern "C" void kernel_launch(void* const* d_in, const int* in_sizes, int n_in,
                              void* d_out, int out_size, void* d_ws, size_t ws_size,
                              hipStream_t stream) {
    const float* node_embed = (const float*)d_in[0];
    const int*   batch      = (const int*)d_in[1];
    const int*   branch     = (const int*)d_in[2];
    const float* W1         = (const float*)d_in[3];
    const float* b1         = (const float*)d_in[4];
    const float* W2         = (const float*)d_in[5];
    const float* b2         = (const float*)d_in[6];
    float*       out        = (float*)d_out;

    const int n_nodes = in_sizes[0] / NCH;   // 2,000,000

    float* part = (float*)d_ws;                                   // 2 x 4 MB partials
    int*   max_b_part = (int*)((char*)d_ws + 2 * (size_t)NGR * NBR * NCH * sizeof(float));

    // both workspace buffers fully overwritten non-atomically every call
    scatter_mfma<<<2 * NGR, 512, 0, stream>>>(node_embed, batch, branch,
                                              part, max_b_part, n_nodes);
    mlp_mfma<<<NGR, 512, 0, stream>>>(part, max_b_part, W1, b1, W2, b2, out);
}